// Round 19
// baseline (47.842 us; speedup 1.0000x reference)
//
#include <hip/hip_runtime.h>

// Fixed-shape problem
#define NBATCH 4
#define NPTS   8192
#define MTGT   8192
#define BN     (NBATCH*NPTS)      // 32768 sources (== total targets)
#define NCHUNK 16                 // target chunks per batch (512 targets each)
#define SGRP   16                 // source groups per batch (512 sources each)
// grid: (16, 16, 4) = 1024 blocks of 256 threads (4 waves)
// per wave: 4 source strips x 16 target tiles = 64 MFMA, 16 B-loads (halved vs R18)

typedef __attribute__((ext_vector_type(8)))  short bf16x8;   // guide-verified frag type
typedef __attribute__((ext_vector_type(16))) float f32x16;

__device__ __forceinline__ unsigned short f2bf(float x) {   // RNE fp32->bf16
    unsigned u = __float_as_uint(x);
    return (unsigned short)((u + 0x7fffu + ((u >> 16) & 1u)) >> 16);
}
__device__ __forceinline__ float bf2f(unsigned short h) {
    return __uint_as_float(((unsigned)h) << 16);
}

// Pack A (sources, scaled by -2, hi/lo split) and B (targets hi/lo + ||t||^2
// 3-way split) into MFMA fragment order (slot pairing validated: R13-R18
// absmax 0.0).
__global__ __launch_bounds__(256) void prep_kernel(const float* __restrict__ src,
                                                   const float* __restrict__ tgt,
                                                   unsigned short* __restrict__ Apk,
                                                   unsigned short* __restrict__ Bpk) {
    const int i = blockIdx.x * 256 + threadIdx.x;   // 0..BN-1
    const int T = i >> 5, l = i & 31;
    const unsigned ONE = 0x3F80u;

    // ---- A: a = -2*s
    float sx = src[3*(size_t)i], sy = src[3*(size_t)i+1], sz = src[3*(size_t)i+2];
    float axf = -2.f*sx, ayf = -2.f*sy, azf = -2.f*sz;
    unsigned axh = f2bf(axf), ayh = f2bf(ayf), azh = f2bf(azf);
    unsigned axl = f2bf(axf - bf2f(axh));
    unsigned ayl = f2bf(ayf - bf2f(ayh));
    unsigned azl = f2bf(azf - bf2f(azh));
    uint4* a0 = (uint4*)(Apk + ((size_t)T*64 +      l) * 8);
    uint4* a1 = (uint4*)(Apk + ((size_t)T*64 + 32 + l) * 8);
    *a0 = make_uint4(axh | (ayh<<16), azh | (axl<<16), ayl | (azl<<16), axh | (ayh<<16));
    *a1 = make_uint4(azh | (ONE<<16), ONE | (ONE<<16), 0u, 0u);

    // ---- B: t hi/lo + tsq 3-split (invalid target -> tsq = 1e30)
    float tx = tgt[3*(size_t)i], ty = tgt[3*(size_t)i+1], tz = tgt[3*(size_t)i+2];
    unsigned txh = f2bf(tx), tyh = f2bf(ty), tzh = f2bf(tz);
    unsigned txl = f2bf(tx - bf2f(txh));
    unsigned tyl = f2bf(ty - bf2f(tyh));
    unsigned tzl = f2bf(tz - bf2f(tzh));
    float tsq = fmaf(tx, tx, fmaf(ty, ty, tz * tz));
    bool valid = (tx != 0.f) || (ty != 0.f) || (tz != 0.f);
    unsigned qh, qm, ql;
    if (valid) {
        qh = f2bf(tsq);
        float r1 = tsq - bf2f(qh); qm = f2bf(r1);
        float r2 = r1 - bf2f(qm);  ql = f2bf(r2);
    } else { qh = f2bf(1e30f); qm = 0u; ql = 0u; }
    uint4* b0 = (uint4*)(Bpk + ((size_t)T*64 +      l) * 8);
    uint4* b1 = (uint4*)(Bpk + ((size_t)T*64 + 32 + l) * 8);
    *b0 = make_uint4(txh | (tyh<<16), tzh | (txh<<16), tyh | (tzh<<16), txl | (tyl<<16));
    *b1 = make_uint4(tzl | (qh<<16), qm | (ql<<16), 0u, 0u);
}

// min over the 16 C-regs + accumulator: 9 v_min3-fusable ops, exact/associative.
__device__ __forceinline__ float min16(const f32x16& d, float acc) {
    float r0 = fminf(fminf(d[0],  d[1]),  d[2]);
    float r1 = fminf(fminf(d[3],  d[4]),  d[5]);
    float r2 = fminf(fminf(d[6],  d[7]),  d[8]);
    float r3 = fminf(fminf(d[9],  d[10]), d[11]);
    float r4 = fminf(fminf(d[12], d[13]), d[14]);
    float s0 = fminf(fminf(r0, r1), r2);
    float s1 = fminf(fminf(r3, r4), d[15]);
    return fminf(fminf(s0, s1), acc);
}

// OPERAND-SWAPPED (validated R15-R18): rows = targets, cols = sources.
// 4 source strips per wave: each loaded B-tile feeds FOUR MFMAs -> B-fragment
// L2 traffic halved vs R18 (134 -> 67 MB), MFMA count unchanged.
__global__ __launch_bounds__(256, 4) void nn_mfma_kernel(const unsigned short* __restrict__ Apk,
                                                         const unsigned short* __restrict__ Bpk,
                                                         float* __restrict__ wspart) {
    const int lane = threadIdx.x & 63, wid = threadIdx.x >> 6;
    const int sg = blockIdx.x, cy = blockIdx.y, bz = blockIdx.z;

    const bf16x8* Ap = (const bf16x8*)Apk;
    const bf16x8* Bp = (const bf16x8*)Bpk;

    const int Ts0 = bz * 256 + sg * 16 + wid * 4;     // 4 source strips (cols)
    bf16x8 s0 = Ap[(size_t)Ts0 * 64 + lane];
    bf16x8 s1 = Ap[(size_t)(Ts0 + 1) * 64 + lane];
    bf16x8 s2 = Ap[(size_t)(Ts0 + 2) * 64 + lane];
    bf16x8 s3 = Ap[(size_t)(Ts0 + 3) * 64 + lane];

    f32x16 z;
#pragma unroll
    for (int e = 0; e < 16; ++e) z[e] = 0.f;
    float acc0 = 3e38f, acc1 = 3e38f, acc2 = 3e38f, acc3 = 3e38f;

    const int Tb0 = bz * 256 + cy * 16;               // 16 target tiles (rows)
    const bf16x8* bp = Bp + (size_t)Tb0 * 64 + lane;

#pragma unroll 2
    for (int m = 0; m < 16; m += 2) {
        bf16x8 tfA = bp[(size_t)m * 64];              // 16B/lane coalesced
        bf16x8 tfB = bp[(size_t)(m + 1) * 64];
        f32x16 d0 = __builtin_amdgcn_mfma_f32_32x32x16_bf16(tfA, s0, z, 0, 0, 0);
        f32x16 d1 = __builtin_amdgcn_mfma_f32_32x32x16_bf16(tfA, s1, z, 0, 0, 0);
        f32x16 d2 = __builtin_amdgcn_mfma_f32_32x32x16_bf16(tfA, s2, z, 0, 0, 0);
        f32x16 d3 = __builtin_amdgcn_mfma_f32_32x32x16_bf16(tfA, s3, z, 0, 0, 0);
        acc0 = min16(d0, acc0);
        acc1 = min16(d1, acc1);
        acc2 = min16(d2, acc2);
        acc3 = min16(d3, acc3);
        f32x16 e0 = __builtin_amdgcn_mfma_f32_32x32x16_bf16(tfB, s0, z, 0, 0, 0);
        f32x16 e1 = __builtin_amdgcn_mfma_f32_32x32x16_bf16(tfB, s1, z, 0, 0, 0);
        f32x16 e2 = __builtin_amdgcn_mfma_f32_32x32x16_bf16(tfB, s2, z, 0, 0, 0);
        f32x16 e3 = __builtin_amdgcn_mfma_f32_32x32x16_bf16(tfB, s3, z, 0, 0, 0);
        acc0 = min16(e0, acc0);
        acc1 = min16(e1, acc1);
        acc2 = min16(e2, acc2);
        acc3 = min16(e3, acc3);
    }

    // combine lane-halves (complementary target rows) -- one swap per strip
    float f0 = fminf(acc0, __shfl_xor(acc0, 32));
    float f1 = fminf(acc1, __shfl_xor(acc1, 32));
    float f2 = fminf(acc2, __shfl_xor(acc2, 32));
    float f3 = fminf(acc3, __shfl_xor(acc3, 32));

    // lane = source col -> four coalesced 128B stores from lanes 0..31
    if (lane < 32) {
        float* wb = wspart + (size_t)cy * BN + (size_t)bz * NPTS + sg * 512 + wid * 128;
        wb[lane]      = f0;
        wb[32 + lane] = f1;
        wb[64 + lane] = f2;
        wb[96 + lane] = f3;
    }
}

// 128 blocks x 256: min over 16 chunk-partials (coalesced), + ||s||^2, validity,
// fixed-order double partials -> bit-deterministic.
__global__ __launch_bounds__(256) void reduce_kernel(const float* __restrict__ src,
                                                     const float* __restrict__ wspart,
                                                     double* __restrict__ partials) {
    const int blk = blockIdx.x, tid = threadIdx.x;
    const int gid = blk * 256 + tid;

    float m = 3e38f;
#pragma unroll 4
    for (int c = 0; c < NCHUNK; ++c) m = fminf(m, wspart[(size_t)c * BN + gid]);

    float sx = src[3*(size_t)gid], sy = src[3*(size_t)gid+1], sz = src[3*(size_t)gid+2];
    bool valid = (sx != 0.f) || (sy != 0.f) || (sz != 0.f);
    float ssq = fmaf(sx, sx, fmaf(sy, sy, sz * sz));
    float sq = fmaxf(0.f, ssq + m);

    __shared__ double sh[512];
    sh[tid] = valid ? (double)sq : 0.0;
    sh[256 + tid] = valid ? 1.0 : 0.0;
    __syncthreads();
    for (int s = 128; s > 0; s >>= 1) {
        if (tid < s) { sh[tid] += sh[tid + s]; sh[256 + tid] += sh[256 + tid + s]; }
        __syncthreads();
    }
    if (tid == 0) { partials[2 * blk] = sh[0]; partials[2 * blk + 1] = sh[256]; }
}

// Fixed-order final combine (batch t owns partial blocks 32t..32t+31).
__global__ void final_kernel(const double* __restrict__ partials, float* __restrict__ out) {
    __shared__ double bmv[4];
    int t = threadIdx.x;
    if (t < 4) {
        double s = 0.0, c = 0.0;
        for (int i = 0; i < 32; ++i) {
            s += partials[2 * (t * 32 + i)];
            c += partials[2 * (t * 32 + i) + 1];
        }
        if (c < 1.0) c = 1.0;
        bmv[t] = s / (3.0 * c);
    }
    __syncthreads();
    if (t == 0) out[0] = (float)((bmv[0] + bmv[1] + bmv[2] + bmv[3]) * 0.25);
}

extern "C" void kernel_launch(void* const* d_in, const int* in_sizes, int n_in,
                              void* d_out, int out_size, void* d_ws, size_t ws_size,
                              hipStream_t stream) {
    const float* src = (const float*)d_in[0];
    const float* tgt = (const float*)d_in[1];
    float* out = (float*)d_out;

    // ws: Apk 1MB | Bpk 1MB | wspart 2MB | partials 2KB
    unsigned short* Apk = (unsigned short*)d_ws;
    unsigned short* Bpk = (unsigned short*)((char*)d_ws + (1u << 20));
    float* wspart       = (float*)((char*)d_ws + (2u << 20));
    double* partials    = (double*)((char*)d_ws + (4u << 20));

    prep_kernel<<<dim3(BN / 256), dim3(256), 0, stream>>>(src, tgt, Apk, Bpk);
    nn_mfma_kernel<<<dim3(SGRP, NCHUNK, NBATCH), dim3(256), 0, stream>>>(Apk, Bpk, wspart);
    reduce_kernel<<<dim3(BN / 256), dim3(256), 0, stream>>>(src, wspart, partials);
    final_kernel<<<dim3(1), dim3(64), 0, stream>>>(partials, out);
}

// Round 20
// 27.586 us; speedup vs baseline: 1.7343x; 1.7343x over previous
//
#include <hip/hip_runtime.h>

// Fixed-shape problem
#define NBATCH 4
#define NPTS   8192
#define MTGT   8192
#define BN     (NBATCH*NPTS)      // 32768 sources (== total targets)
#define NCHUNK 16                 // target chunks per batch (512 targets each)
#define SGRP   16                 // source groups per batch (512 sources each)
// grid: (16, 16, 4) = 1024 blocks of 256 threads (4 waves)
// per wave: 4 source strips x 16 target tiles = 64 MFMA, 16 B-loads (half of R18)
// SPILL-SAFE: one B-tile per iteration -> max 4 f32x16 live (~110 VGPR < 128 cap)

typedef __attribute__((ext_vector_type(8)))  short bf16x8;   // guide-verified frag type
typedef __attribute__((ext_vector_type(16))) float f32x16;

__device__ __forceinline__ unsigned short f2bf(float x) {   // RNE fp32->bf16
    unsigned u = __float_as_uint(x);
    return (unsigned short)((u + 0x7fffu + ((u >> 16) & 1u)) >> 16);
}
__device__ __forceinline__ float bf2f(unsigned short h) {
    return __uint_as_float(((unsigned)h) << 16);
}

// Pack A (sources, scaled by -2, hi/lo split) and B (targets hi/lo + ||t||^2
// 3-way split) into MFMA fragment order (slot pairing validated: R13-R19
// absmax 0.0).
__global__ __launch_bounds__(256) void prep_kernel(const float* __restrict__ src,
                                                   const float* __restrict__ tgt,
                                                   unsigned short* __restrict__ Apk,
                                                   unsigned short* __restrict__ Bpk) {
    const int i = blockIdx.x * 256 + threadIdx.x;   // 0..BN-1
    const int T = i >> 5, l = i & 31;
    const unsigned ONE = 0x3F80u;

    // ---- A: a = -2*s
    float sx = src[3*(size_t)i], sy = src[3*(size_t)i+1], sz = src[3*(size_t)i+2];
    float axf = -2.f*sx, ayf = -2.f*sy, azf = -2.f*sz;
    unsigned axh = f2bf(axf), ayh = f2bf(ayf), azh = f2bf(azf);
    unsigned axl = f2bf(axf - bf2f(axh));
    unsigned ayl = f2bf(ayf - bf2f(ayh));
    unsigned azl = f2bf(azf - bf2f(azh));
    uint4* a0 = (uint4*)(Apk + ((size_t)T*64 +      l) * 8);
    uint4* a1 = (uint4*)(Apk + ((size_t)T*64 + 32 + l) * 8);
    *a0 = make_uint4(axh | (ayh<<16), azh | (axl<<16), ayl | (azl<<16), axh | (ayh<<16));
    *a1 = make_uint4(azh | (ONE<<16), ONE | (ONE<<16), 0u, 0u);

    // ---- B: t hi/lo + tsq 3-split (invalid target -> tsq = 1e30)
    float tx = tgt[3*(size_t)i], ty = tgt[3*(size_t)i+1], tz = tgt[3*(size_t)i+2];
    unsigned txh = f2bf(tx), tyh = f2bf(ty), tzh = f2bf(tz);
    unsigned txl = f2bf(tx - bf2f(txh));
    unsigned tyl = f2bf(ty - bf2f(tyh));
    unsigned tzl = f2bf(tz - bf2f(tzh));
    float tsq = fmaf(tx, tx, fmaf(ty, ty, tz * tz));
    bool valid = (tx != 0.f) || (ty != 0.f) || (tz != 0.f);
    unsigned qh, qm, ql;
    if (valid) {
        qh = f2bf(tsq);
        float r1 = tsq - bf2f(qh); qm = f2bf(r1);
        float r2 = r1 - bf2f(qm);  ql = f2bf(r2);
    } else { qh = f2bf(1e30f); qm = 0u; ql = 0u; }
    uint4* b0 = (uint4*)(Bpk + ((size_t)T*64 +      l) * 8);
    uint4* b1 = (uint4*)(Bpk + ((size_t)T*64 + 32 + l) * 8);
    *b0 = make_uint4(txh | (tyh<<16), tzh | (txh<<16), tyh | (tzh<<16), txl | (tyl<<16));
    *b1 = make_uint4(tzl | (qh<<16), qm | (ql<<16), 0u, 0u);
}

// min over the 16 C-regs + accumulator: 9 v_min3-fusable ops, exact/associative.
__device__ __forceinline__ float min16(const f32x16& d, float acc) {
    float r0 = fminf(fminf(d[0],  d[1]),  d[2]);
    float r1 = fminf(fminf(d[3],  d[4]),  d[5]);
    float r2 = fminf(fminf(d[6],  d[7]),  d[8]);
    float r3 = fminf(fminf(d[9],  d[10]), d[11]);
    float r4 = fminf(fminf(d[12], d[13]), d[14]);
    float s0 = fminf(fminf(r0, r1), r2);
    float s1 = fminf(fminf(r3, r4), d[15]);
    return fminf(fminf(s0, s1), acc);
}

// OPERAND-SWAPPED (validated R15-R19): rows = targets, cols = sources.
// 4 source strips per wave, ONE B-tile per iteration: each load feeds four
// MFMAs (B L2-traffic halved vs R18) with only 4 f32x16 live (no spill --
// R19's 2-tile body held 8 live = 128 VGPRs and spilled).
__global__ __launch_bounds__(256, 4) void nn_mfma_kernel(const unsigned short* __restrict__ Apk,
                                                         const unsigned short* __restrict__ Bpk,
                                                         float* __restrict__ wspart) {
    const int lane = threadIdx.x & 63, wid = threadIdx.x >> 6;
    const int sg = blockIdx.x, cy = blockIdx.y, bz = blockIdx.z;

    const bf16x8* Ap = (const bf16x8*)Apk;
    const bf16x8* Bp = (const bf16x8*)Bpk;

    const int Ts0 = bz * 256 + sg * 16 + wid * 4;     // 4 source strips (cols)
    bf16x8 s0 = Ap[(size_t)Ts0 * 64 + lane];
    bf16x8 s1 = Ap[(size_t)(Ts0 + 1) * 64 + lane];
    bf16x8 s2 = Ap[(size_t)(Ts0 + 2) * 64 + lane];
    bf16x8 s3 = Ap[(size_t)(Ts0 + 3) * 64 + lane];

    f32x16 z;
#pragma unroll
    for (int e = 0; e < 16; ++e) z[e] = 0.f;
    float acc0 = 3e38f, acc1 = 3e38f, acc2 = 3e38f, acc3 = 3e38f;

    const int Tb0 = bz * 256 + cy * 16;               // 16 target tiles (rows)
    const bf16x8* bp = Bp + (size_t)Tb0 * 64 + lane;

#pragma unroll 1
    for (int m = 0; m < 16; ++m) {
        bf16x8 tf = bp[(size_t)m * 64];               // 16B/lane coalesced
        f32x16 d0 = __builtin_amdgcn_mfma_f32_32x32x16_bf16(tf, s0, z, 0, 0, 0);
        f32x16 d1 = __builtin_amdgcn_mfma_f32_32x32x16_bf16(tf, s1, z, 0, 0, 0);
        f32x16 d2 = __builtin_amdgcn_mfma_f32_32x32x16_bf16(tf, s2, z, 0, 0, 0);
        f32x16 d3 = __builtin_amdgcn_mfma_f32_32x32x16_bf16(tf, s3, z, 0, 0, 0);
        acc0 = min16(d0, acc0);
        acc1 = min16(d1, acc1);
        acc2 = min16(d2, acc2);
        acc3 = min16(d3, acc3);
    }

    // combine lane-halves (complementary target rows) -- one swap per strip
    float f0 = fminf(acc0, __shfl_xor(acc0, 32));
    float f1 = fminf(acc1, __shfl_xor(acc1, 32));
    float f2 = fminf(acc2, __shfl_xor(acc2, 32));
    float f3 = fminf(acc3, __shfl_xor(acc3, 32));

    // lane = source col -> four coalesced 128B stores from lanes 0..31
    if (lane < 32) {
        float* wb = wspart + (size_t)cy * BN + (size_t)bz * NPTS + sg * 512 + wid * 128;
        wb[lane]      = f0;
        wb[32 + lane] = f1;
        wb[64 + lane] = f2;
        wb[96 + lane] = f3;
    }
}

// 128 blocks x 256: min over 16 chunk-partials (coalesced), + ||s||^2, validity,
// fixed-order double partials -> bit-deterministic.
__global__ __launch_bounds__(256) void reduce_kernel(const float* __restrict__ src,
                                                     const float* __restrict__ wspart,
                                                     double* __restrict__ partials) {
    const int blk = blockIdx.x, tid = threadIdx.x;
    const int gid = blk * 256 + tid;

    float m = 3e38f;
#pragma unroll 4
    for (int c = 0; c < NCHUNK; ++c) m = fminf(m, wspart[(size_t)c * BN + gid]);

    float sx = src[3*(size_t)gid], sy = src[3*(size_t)gid+1], sz = src[3*(size_t)gid+2];
    bool valid = (sx != 0.f) || (sy != 0.f) || (sz != 0.f);
    float ssq = fmaf(sx, sx, fmaf(sy, sy, sz * sz));
    float sq = fmaxf(0.f, ssq + m);

    __shared__ double sh[512];
    sh[tid] = valid ? (double)sq : 0.0;
    sh[256 + tid] = valid ? 1.0 : 0.0;
    __syncthreads();
    for (int s = 128; s > 0; s >>= 1) {
        if (tid < s) { sh[tid] += sh[tid + s]; sh[256 + tid] += sh[256 + tid + s]; }
        __syncthreads();
    }
    if (tid == 0) { partials[2 * blk] = sh[0]; partials[2 * blk + 1] = sh[256]; }
}

// Fixed-order final combine (batch t owns partial blocks 32t..32t+31).
__global__ void final_kernel(const double* __restrict__ partials, float* __restrict__ out) {
    __shared__ double bmv[4];
    int t = threadIdx.x;
    if (t < 4) {
        double s = 0.0, c = 0.0;
        for (int i = 0; i < 32; ++i) {
            s += partials[2 * (t * 32 + i)];
            c += partials[2 * (t * 32 + i) + 1];
        }
        if (c < 1.0) c = 1.0;
        bmv[t] = s / (3.0 * c);
    }
    __syncthreads();
    if (t == 0) out[0] = (float)((bmv[0] + bmv[1] + bmv[2] + bmv[3]) * 0.25);
}

extern "C" void kernel_launch(void* const* d_in, const int* in_sizes, int n_in,
                              void* d_out, int out_size, void* d_ws, size_t ws_size,
                              hipStream_t stream) {
    const float* src = (const float*)d_in[0];
    const float* tgt = (const float*)d_in[1];
    float* out = (float*)d_out;

    // ws: Apk 1MB | Bpk 1MB | wspart 2MB | partials 2KB
    unsigned short* Apk = (unsigned short*)d_ws;
    unsigned short* Bpk = (unsigned short*)((char*)d_ws + (1u << 20));
    float* wspart       = (float*)((char*)d_ws + (2u << 20));
    double* partials    = (double*)((char*)d_ws + (4u << 20));

    prep_kernel<<<dim3(BN / 256), dim3(256), 0, stream>>>(src, tgt, Apk, Bpk);
    nn_mfma_kernel<<<dim3(SGRP, NCHUNK, NBATCH), dim3(256), 0, stream>>>(Apk, Bpk, wspart);
    reduce_kernel<<<dim3(BN / 256), dim3(256), 0, stream>>>(src, wspart, partials);
    final_kernel<<<dim3(1), dim3(64), 0, stream>>>(partials, out);
}

// Round 21
// 25.543 us; speedup vs baseline: 1.8730x; 1.0800x over previous
//
#include <hip/hip_runtime.h>

// Fixed-shape problem
#define NBATCH 4
#define NPTS   8192
#define MTGT   8192
#define BN     (NBATCH*NPTS)      // 32768 sources (== total targets)
#define NCHUNK 8                  // target chunks per batch (1024 targets each)
#define SGRP   32                 // source groups per batch (256 sources each)
// nn grid: (32, 8, 4) = 1024 blocks of 256 threads (4 waves)

typedef __attribute__((ext_vector_type(8)))  short bf16x8;   // guide-verified frag type
typedef __attribute__((ext_vector_type(16))) float f32x16;

__device__ __forceinline__ unsigned short f2bf(float x) {   // RNE fp32->bf16
    unsigned u = __float_as_uint(x);
    return (unsigned short)((u + 0x7fffu + ((u >> 16) & 1u)) >> 16);
}
__device__ __forceinline__ float bf2f(unsigned short h) {
    return __uint_as_float(((unsigned)h) << 16);
}

// Pack A (sources, scaled by -2, hi/lo split) and B (targets hi/lo + ||t||^2
// 3-way split) into MFMA fragment order (slot pairing validated: R13-R20
// absmax 0.0). Also zeroes out[0] each call (graph replays re-accumulate).
__global__ __launch_bounds__(256) void prep_kernel(const float* __restrict__ src,
                                                   const float* __restrict__ tgt,
                                                   unsigned short* __restrict__ Apk,
                                                   unsigned short* __restrict__ Bpk,
                                                   float* __restrict__ out) {
    const int i = blockIdx.x * 256 + threadIdx.x;   // 0..BN-1
    const int T = i >> 5, l = i & 31;
    const unsigned ONE = 0x3F80u;
    if (i == 0) out[0] = 0.f;

    // ---- A: a = -2*s
    float sx = src[3*(size_t)i], sy = src[3*(size_t)i+1], sz = src[3*(size_t)i+2];
    float axf = -2.f*sx, ayf = -2.f*sy, azf = -2.f*sz;
    unsigned axh = f2bf(axf), ayh = f2bf(ayf), azh = f2bf(azf);
    unsigned axl = f2bf(axf - bf2f(axh));
    unsigned ayl = f2bf(ayf - bf2f(ayh));
    unsigned azl = f2bf(azf - bf2f(azh));
    uint4* a0 = (uint4*)(Apk + ((size_t)T*64 +      l) * 8);
    uint4* a1 = (uint4*)(Apk + ((size_t)T*64 + 32 + l) * 8);
    *a0 = make_uint4(axh | (ayh<<16), azh | (axl<<16), ayl | (azl<<16), axh | (ayh<<16));
    *a1 = make_uint4(azh | (ONE<<16), ONE | (ONE<<16), 0u, 0u);

    // ---- B: t hi/lo + tsq 3-split (invalid target -> tsq = 1e30)
    float tx = tgt[3*(size_t)i], ty = tgt[3*(size_t)i+1], tz = tgt[3*(size_t)i+2];
    unsigned txh = f2bf(tx), tyh = f2bf(ty), tzh = f2bf(tz);
    unsigned txl = f2bf(tx - bf2f(txh));
    unsigned tyl = f2bf(ty - bf2f(tyh));
    unsigned tzl = f2bf(tz - bf2f(tzh));
    float tsq = fmaf(tx, tx, fmaf(ty, ty, tz * tz));
    bool valid = (tx != 0.f) || (ty != 0.f) || (tz != 0.f);
    unsigned qh, qm, ql;
    if (valid) {
        qh = f2bf(tsq);
        float r1 = tsq - bf2f(qh); qm = f2bf(r1);
        float r2 = r1 - bf2f(qm);  ql = f2bf(r2);
    } else { qh = f2bf(1e30f); qm = 0u; ql = 0u; }
    uint4* b0 = (uint4*)(Bpk + ((size_t)T*64 +      l) * 8);
    uint4* b1 = (uint4*)(Bpk + ((size_t)T*64 + 32 + l) * 8);
    *b0 = make_uint4(txh | (tyh<<16), tzh | (txh<<16), tyh | (tzh<<16), txl | (tyl<<16));
    *b1 = make_uint4(tzl | (qh<<16), qm | (ql<<16), 0u, 0u);
}

// min over the 16 C-regs + accumulator: 9 v_min3-fusable ops, exact/associative.
__device__ __forceinline__ float min16(const f32x16& d, float acc) {
    float r0 = fminf(fminf(d[0],  d[1]),  d[2]);
    float r1 = fminf(fminf(d[3],  d[4]),  d[5]);
    float r2 = fminf(fminf(d[6],  d[7]),  d[8]);
    float r3 = fminf(fminf(d[9],  d[10]), d[11]);
    float r4 = fminf(fminf(d[12], d[13]), d[14]);
    float s0 = fminf(fminf(r0, r1), r2);
    float s1 = fminf(fminf(r3, r4), d[15]);
    return fminf(fminf(s0, s1), acc);
}

// R18's EXACT nn kernel (fastest proven, 23.3us total): operand-swapped
// (rows = targets, cols = sources), 2 source strips x 2 B-tiles per body --
// 4 f32x16 live (no spill), 2 loads in flight (latency hidden), min16 trees
// + ONE shfl_xor(32) per strip.
__global__ __launch_bounds__(256, 4) void nn_mfma_kernel(const unsigned short* __restrict__ Apk,
                                                         const unsigned short* __restrict__ Bpk,
                                                         float* __restrict__ wspart) {
    const int lane = threadIdx.x & 63, wid = threadIdx.x >> 6;
    const int sg = blockIdx.x, cy = blockIdx.y, bz = blockIdx.z;

    const bf16x8* Ap = (const bf16x8*)Apk;
    const bf16x8* Bp = (const bf16x8*)Bpk;

    const int Ts0 = bz * 256 + sg * 8 + wid * 2;      // 2 source strips (cols)
    bf16x8 s0 = Ap[(size_t)Ts0 * 64 + lane];
    bf16x8 s1 = Ap[(size_t)(Ts0 + 1) * 64 + lane];

    f32x16 z;
#pragma unroll
    for (int e = 0; e < 16; ++e) z[e] = 0.f;
    float acc0 = 3e38f, acc1 = 3e38f;

    const int Tb0 = bz * 256 + cy * 32;               // 32 target tiles (rows)
    const bf16x8* bp = Bp + (size_t)Tb0 * 64 + lane;

#pragma unroll 2
    for (int m = 0; m < 32; m += 2) {
        bf16x8 tfA = bp[(size_t)m * 64];              // 16B/lane coalesced, L1-shared
        bf16x8 tfB = bp[(size_t)(m + 1) * 64];
        f32x16 d0 = __builtin_amdgcn_mfma_f32_32x32x16_bf16(tfA, s0, z, 0, 0, 0);
        f32x16 d1 = __builtin_amdgcn_mfma_f32_32x32x16_bf16(tfA, s1, z, 0, 0, 0);
        f32x16 d2 = __builtin_amdgcn_mfma_f32_32x32x16_bf16(tfB, s0, z, 0, 0, 0);
        f32x16 d3 = __builtin_amdgcn_mfma_f32_32x32x16_bf16(tfB, s1, z, 0, 0, 0);
        acc0 = min16(d0, acc0);
        acc1 = min16(d1, acc1);
        acc0 = min16(d2, acc0);
        acc1 = min16(d3, acc1);
    }

    // combine lane-halves (complementary target rows) -- one swap per strip
    float f0 = fminf(acc0, __shfl_xor(acc0, 32));
    float f1 = fminf(acc1, __shfl_xor(acc1, 32));

    // lane = source col -> coalesced 128B stores from lanes 0..31
    if (lane < 32) {
        float* wb = wspart + (size_t)cy * BN + (size_t)bz * NPTS + sg * 256 + wid * 64;
        wb[lane]      = f0;
        wb[32 + lane] = f1;
    }
}

// MERGED reduce+final: 4 blocks (one per batch) x 1024 threads. Each thread
// owns 8 sources (fixed k-order), block does a fixed LDS tree (deterministic),
// then ONE float atomicAdd of batch_mean/4 into out (4-value add-order
// nondeterminism ~1 ulp << 1.59e-4 threshold). Saves one dispatch.
__global__ __launch_bounds__(1024) void reduce_kernel(const float* __restrict__ src,
                                                      const float* __restrict__ wspart,
                                                      float* __restrict__ out) {
    const int b = blockIdx.x;          // batch
    const int tid = threadIdx.x;       // 0..1023

    double sum = 0.0, cnt = 0.0;
#pragma unroll
    for (int k = 0; k < 8; ++k) {
        const int gid = b * NPTS + k * 1024 + tid;   // coalesced per (k,c)
        float m = 3e38f;
#pragma unroll
        for (int c = 0; c < NCHUNK; ++c) m = fminf(m, wspart[(size_t)c * BN + gid]);
        float sx = src[3*(size_t)gid], sy = src[3*(size_t)gid+1], sz = src[3*(size_t)gid+2];
        bool valid = (sx != 0.f) || (sy != 0.f) || (sz != 0.f);
        float ssq = fmaf(sx, sx, fmaf(sy, sy, sz * sz));
        float sq = fmaxf(0.f, ssq + m);
        if (valid) { sum += (double)sq; cnt += 1.0; }
    }

    __shared__ double sh[2048];
    sh[tid] = sum; sh[1024 + tid] = cnt;
    __syncthreads();
    for (int s = 512; s > 0; s >>= 1) {
        if (tid < s) { sh[tid] += sh[tid + s]; sh[1024 + tid] += sh[1024 + tid + s]; }
        __syncthreads();
    }
    if (tid == 0) {
        double c = sh[1024] > 1.0 ? sh[1024] : 1.0;
        atomicAdd(out, (float)(sh[0] / (3.0 * c) * 0.25));
    }
}

extern "C" void kernel_launch(void* const* d_in, const int* in_sizes, int n_in,
                              void* d_out, int out_size, void* d_ws, size_t ws_size,
                              hipStream_t stream) {
    const float* src = (const float*)d_in[0];
    const float* tgt = (const float*)d_in[1];
    float* out = (float*)d_out;

    // ws: Apk 1MB | Bpk 1MB | wspart 1MB
    unsigned short* Apk = (unsigned short*)d_ws;
    unsigned short* Bpk = (unsigned short*)((char*)d_ws + (1u << 20));
    float* wspart       = (float*)((char*)d_ws + (2u << 20));

    prep_kernel<<<dim3(BN / 256), dim3(256), 0, stream>>>(src, tgt, Apk, Bpk, out);
    nn_mfma_kernel<<<dim3(SGRP, NCHUNK, NBATCH), dim3(256), 0, stream>>>(Apk, Bpk, wspart);
    reduce_kernel<<<dim3(NBATCH), dim3(1024), 0, stream>>>(src, wspart, out);
}

// Round 22
// 22.366 us; speedup vs baseline: 2.1391x; 1.1420x over previous
//
#include <hip/hip_runtime.h>

// Fixed-shape problem
#define NBATCH 4
#define NPTS   8192
#define MTGT   8192
#define BN     (NBATCH*NPTS)      // 32768 sources (== total targets)
#define NCHUNK 8                  // target chunks per batch (1024 targets each)
#define SGRP   32                 // source groups per batch (256 sources each)
// nn grid: (32, 8, 4) = 1024 blocks of 256 threads (4 waves)

typedef __attribute__((ext_vector_type(8)))  short bf16x8;   // guide-verified frag type
typedef __attribute__((ext_vector_type(16))) float f32x16;

__device__ __forceinline__ unsigned short f2bf(float x) {   // RNE fp32->bf16
    unsigned u = __float_as_uint(x);
    return (unsigned short)((u + 0x7fffu + ((u >> 16) & 1u)) >> 16);
}
__device__ __forceinline__ float bf2f(unsigned short h) {
    return __uint_as_float(((unsigned)h) << 16);
}

// Pack A (sources, scaled by -2, hi/lo split) and B (targets hi/lo + ||t||^2
// 3-way split) into MFMA fragment order (slot pairing validated: R13-R21
// absmax 0.0).
__global__ __launch_bounds__(256) void prep_kernel(const float* __restrict__ src,
                                                   const float* __restrict__ tgt,
                                                   unsigned short* __restrict__ Apk,
                                                   unsigned short* __restrict__ Bpk) {
    const int i = blockIdx.x * 256 + threadIdx.x;   // 0..BN-1
    const int T = i >> 5, l = i & 31;
    const unsigned ONE = 0x3F80u;

    // ---- A: a = -2*s
    float sx = src[3*(size_t)i], sy = src[3*(size_t)i+1], sz = src[3*(size_t)i+2];
    float axf = -2.f*sx, ayf = -2.f*sy, azf = -2.f*sz;
    unsigned axh = f2bf(axf), ayh = f2bf(ayf), azh = f2bf(azf);
    unsigned axl = f2bf(axf - bf2f(axh));
    unsigned ayl = f2bf(ayf - bf2f(ayh));
    unsigned azl = f2bf(azf - bf2f(azh));
    uint4* a0 = (uint4*)(Apk + ((size_t)T*64 +      l) * 8);
    uint4* a1 = (uint4*)(Apk + ((size_t)T*64 + 32 + l) * 8);
    *a0 = make_uint4(axh | (ayh<<16), azh | (axl<<16), ayl | (azl<<16), axh | (ayh<<16));
    *a1 = make_uint4(azh | (ONE<<16), ONE | (ONE<<16), 0u, 0u);

    // ---- B: t hi/lo + tsq 3-split (invalid target -> tsq = 1e30)
    float tx = tgt[3*(size_t)i], ty = tgt[3*(size_t)i+1], tz = tgt[3*(size_t)i+2];
    unsigned txh = f2bf(tx), tyh = f2bf(ty), tzh = f2bf(tz);
    unsigned txl = f2bf(tx - bf2f(txh));
    unsigned tyl = f2bf(ty - bf2f(tyh));
    unsigned tzl = f2bf(tz - bf2f(tzh));
    float tsq = fmaf(tx, tx, fmaf(ty, ty, tz * tz));
    bool valid = (tx != 0.f) || (ty != 0.f) || (tz != 0.f);
    unsigned qh, qm, ql;
    if (valid) {
        qh = f2bf(tsq);
        float r1 = tsq - bf2f(qh); qm = f2bf(r1);
        float r2 = r1 - bf2f(qm);  ql = f2bf(r2);
    } else { qh = f2bf(1e30f); qm = 0u; ql = 0u; }
    uint4* b0 = (uint4*)(Bpk + ((size_t)T*64 +      l) * 8);
    uint4* b1 = (uint4*)(Bpk + ((size_t)T*64 + 32 + l) * 8);
    *b0 = make_uint4(txh | (tyh<<16), tzh | (txh<<16), tyh | (tzh<<16), txl | (tyl<<16));
    *b1 = make_uint4(tzl | (qh<<16), qm | (ql<<16), 0u, 0u);
}

// min over the 16 C-regs + accumulator: 8 v_min3-fusable ops, exact/associative.
__device__ __forceinline__ float min16(const f32x16& d, float acc) {
    float r0 = fminf(fminf(d[0],  d[1]),  d[2]);
    float r1 = fminf(fminf(d[3],  d[4]),  d[5]);
    float r2 = fminf(fminf(d[6],  d[7]),  d[8]);
    float r3 = fminf(fminf(d[9],  d[10]), d[11]);
    float r4 = fminf(fminf(d[12], d[13]), d[14]);
    float s0 = fminf(fminf(r0, r1), r2);
    float s1 = fminf(fminf(r3, r4), d[15]);
    return fminf(fminf(s0, s1), acc);
}

// R18's nn kernel + LDS B-staging. All 4 waves of a block consume the SAME
// 32KB B-chunk; 4 resident blocks/CU = 128KB hot B thrashing the 32KB L1 ->
// stage chunk into LDS once (coalesced 128B/thread), m-loop reads become
// conflict-free lane-consecutive ds_read_b128. L2 B-traffic 134 -> 33MB.
// Math/indexing identical to R18 -> bit-identical result.
__global__ __launch_bounds__(256, 4) void nn_mfma_kernel(const unsigned short* __restrict__ Apk,
                                                         const unsigned short* __restrict__ Bpk,
                                                         float* __restrict__ wspart) {
    __shared__ uint4 ldsB[2048];                      // 32KB: 32 tiles x 1KB

    const int tid  = threadIdx.x;
    const int lane = tid & 63, wid = tid >> 6;
    const int sg = blockIdx.x, cy = blockIdx.y, bz = blockIdx.z;

    const bf16x8* Ap = (const bf16x8*)Apk;

    // ---- stage B-chunk (32 tiles, linear): 256 threads x 8 uint4 ----
    const int Tb0 = bz * 256 + cy * 32;               // first tile of chunk
    const uint4* gB = (const uint4*)(Bpk + (size_t)Tb0 * 512);  // tile = 512 shorts
#pragma unroll
    for (int j = 0; j < 8; ++j)
        ldsB[j * 256 + tid] = gB[j * 256 + tid];

    const int Ts0 = bz * 256 + sg * 8 + wid * 2;      // 2 source strips (cols)
    bf16x8 s0 = Ap[(size_t)Ts0 * 64 + lane];
    bf16x8 s1 = Ap[(size_t)(Ts0 + 1) * 64 + lane];

    f32x16 z;
#pragma unroll
    for (int e = 0; e < 16; ++e) z[e] = 0.f;
    float acc0 = 3e38f, acc1 = 3e38f;

    __syncthreads();
    const bf16x8* bp = (const bf16x8*)ldsB;           // [tile*64 + lane]

#pragma unroll 2
    for (int m = 0; m < 32; m += 2) {
        bf16x8 tfA = bp[m * 64 + lane];               // ds_read_b128, conflict-free
        bf16x8 tfB = bp[(m + 1) * 64 + lane];
        f32x16 d0 = __builtin_amdgcn_mfma_f32_32x32x16_bf16(tfA, s0, z, 0, 0, 0);
        f32x16 d1 = __builtin_amdgcn_mfma_f32_32x32x16_bf16(tfA, s1, z, 0, 0, 0);
        f32x16 d2 = __builtin_amdgcn_mfma_f32_32x32x16_bf16(tfB, s0, z, 0, 0, 0);
        f32x16 d3 = __builtin_amdgcn_mfma_f32_32x32x16_bf16(tfB, s1, z, 0, 0, 0);
        acc0 = min16(d0, acc0);
        acc1 = min16(d1, acc1);
        acc0 = min16(d2, acc0);
        acc1 = min16(d3, acc1);
    }

    // combine lane-halves (complementary target rows) -- one swap per strip
    float f0 = fminf(acc0, __shfl_xor(acc0, 32));
    float f1 = fminf(acc1, __shfl_xor(acc1, 32));

    // lane = source col -> coalesced 128B stores from lanes 0..31
    if (lane < 32) {
        float* wb = wspart + (size_t)cy * BN + (size_t)bz * NPTS + sg * 256 + wid * 64;
        wb[lane]      = f0;
        wb[32 + lane] = f1;
    }
}

// 128 blocks x 256: min over 8 chunk-partials (coalesced), + ||s||^2, validity,
// fixed-order double partials -> bit-deterministic. (R18's exact tail.)
__global__ __launch_bounds__(256) void reduce_kernel(const float* __restrict__ src,
                                                     const float* __restrict__ wspart,
                                                     double* __restrict__ partials) {
    const int blk = blockIdx.x, tid = threadIdx.x;
    const int gid = blk * 256 + tid;

    float m = 3e38f;
#pragma unroll
    for (int c = 0; c < NCHUNK; ++c) m = fminf(m, wspart[(size_t)c * BN + gid]);

    float sx = src[3*(size_t)gid], sy = src[3*(size_t)gid+1], sz = src[3*(size_t)gid+2];
    bool valid = (sx != 0.f) || (sy != 0.f) || (sz != 0.f);
    float ssq = fmaf(sx, sx, fmaf(sy, sy, sz * sz));
    float sq = fmaxf(0.f, ssq + m);

    __shared__ double sh[512];
    sh[tid] = valid ? (double)sq : 0.0;
    sh[256 + tid] = valid ? 1.0 : 0.0;
    __syncthreads();
    for (int s = 128; s > 0; s >>= 1) {
        if (tid < s) { sh[tid] += sh[tid + s]; sh[256 + tid] += sh[256 + tid + s]; }
        __syncthreads();
    }
    if (tid == 0) { partials[2 * blk] = sh[0]; partials[2 * blk + 1] = sh[256]; }
}

// Fixed-order final combine (batch t owns partial blocks 32t..32t+31).
__global__ void final_kernel(const double* __restrict__ partials, float* __restrict__ out) {
    __shared__ double bmv[4];
    int t = threadIdx.x;
    if (t < 4) {
        double s = 0.0, c = 0.0;
        for (int i = 0; i < 32; ++i) {
            s += partials[2 * (t * 32 + i)];
            c += partials[2 * (t * 32 + i) + 1];
        }
        if (c < 1.0) c = 1.0;
        bmv[t] = s / (3.0 * c);
    }
    __syncthreads();
    if (t == 0) out[0] = (float)((bmv[0] + bmv[1] + bmv[2] + bmv[3]) * 0.25);
}

extern "C" void kernel_launch(void* const* d_in, const int* in_sizes, int n_in,
                              void* d_out, int out_size, void* d_ws, size_t ws_size,
                              hipStream_t stream) {
    const float* src = (const float*)d_in[0];
    const float* tgt = (const float*)d_in[1];
    float* out = (float*)d_out;

    // ws: Apk 1MB | Bpk 1MB | wspart 1MB | partials 2KB
    unsigned short* Apk = (unsigned short*)d_ws;
    unsigned short* Bpk = (unsigned short*)((char*)d_ws + (1u << 20));
    float* wspart       = (float*)((char*)d_ws + (2u << 20));
    double* partials    = (double*)((char*)d_ws + (3u << 20));

    prep_kernel<<<dim3(BN / 256), dim3(256), 0, stream>>>(src, tgt, Apk, Bpk);
    nn_mfma_kernel<<<dim3(SGRP, NCHUNK, NBATCH), dim3(256), 0, stream>>>(Apk, Bpk, wspart);
    reduce_kernel<<<dim3(BN / 256), dim3(256), 0, stream>>>(src, wspart, partials);
    final_kernel<<<dim3(1), dim3(64), 0, stream>>>(partials, out);
}

// Round 23
// 17.975 us; speedup vs baseline: 2.6616x; 1.2443x over previous
//
#include <hip/hip_runtime.h>

// Fixed-shape problem
#define NBATCH 4
#define NPTS   8192
#define MTGT   8192
#define BN     (NBATCH*NPTS)      // 32768 sources (== total targets)
#define NCHUNK 8                  // target chunks per batch (1024 targets each)
#define SGRP   32                 // source groups per batch (256 sources each)
// nn grid: (32, 8, 4) = 1024 blocks of 256 threads (4 waves)

typedef __attribute__((ext_vector_type(8)))  short bf16x8;   // guide-verified frag type
typedef __attribute__((ext_vector_type(16))) float f32x16;

__device__ __forceinline__ unsigned short f2bf(float x) {   // RNE fp32->bf16
    unsigned u = __float_as_uint(x);
    return (unsigned short)((u + 0x7fffu + ((u >> 16) & 1u)) >> 16);
}
__device__ __forceinline__ float bf2f(unsigned short h) {
    return __uint_as_float(((unsigned)h) << 16);
}

// min over the 16 C-regs + accumulator: 8 v_min3-fusable ops, exact/associative.
__device__ __forceinline__ float min16(const f32x16& d, float acc) {
    float r0 = fminf(fminf(d[0],  d[1]),  d[2]);
    float r1 = fminf(fminf(d[3],  d[4]),  d[5]);
    float r2 = fminf(fminf(d[6],  d[7]),  d[8]);
    float r3 = fminf(fminf(d[9],  d[10]), d[11]);
    float r4 = fminf(fminf(d[12], d[13]), d[14]);
    float s0 = fminf(fminf(r0, r1), r2);
    float s1 = fminf(fminf(r3, r4), d[15]);
    return fminf(fminf(s0, s1), acc);
}

// Pack one target (x,y,z) into its b0/b1 fragment words (byte-identical to
// the old prep_kernel math; slot pairing validated R13-R22, absmax 0.0).
__device__ __forceinline__ void packB(float tx, float ty, float tz,
                                      uint4& b0, uint4& b1) {
    unsigned txh = f2bf(tx), tyh = f2bf(ty), tzh = f2bf(tz);
    unsigned txl = f2bf(tx - bf2f(txh));
    unsigned tyl = f2bf(ty - bf2f(tyh));
    unsigned tzl = f2bf(tz - bf2f(tzh));
    float tsq = fmaf(tx, tx, fmaf(ty, ty, tz * tz));
    bool valid = (tx != 0.f) || (ty != 0.f) || (tz != 0.f);
    unsigned qh, qm, ql;
    if (valid) {
        qh = f2bf(tsq);
        float r1 = tsq - bf2f(qh); qm = f2bf(r1);
        float r2 = r1 - bf2f(qm);  ql = f2bf(r2);
    } else { qh = f2bf(1e30f); qm = 0u; ql = 0u; }
    b0 = make_uint4(txh | (tyh<<16), tzh | (txh<<16), tyh | (tzh<<16), txl | (tyl<<16));
    b1 = make_uint4(tzl | (qh<<16), qm | (ql<<16), 0u, 0u);
}

// FUSED prep+nn: A-fragments computed in-register per wave (lane derives its
// own 16B fragment from its source's raw 12B); B-chunk packed block-locally
// straight into LDS (each thread packs 4 targets). Math byte-identical to the
// old prep -> wspart bit-identical to R22. One fewer dispatch, no 2MB
// Apk/Bpk round-trip.
__global__ __launch_bounds__(256, 4) void nn_mfma_kernel(const float* __restrict__ src,
                                                         const float* __restrict__ tgt,
                                                         float* __restrict__ wspart) {
    __shared__ uint4 ldsB[2048];                      // 32KB: 32 tiles x 64 entries

    const int tid  = threadIdx.x;
    const int lane = tid & 63, wid = tid >> 6;
    const int sg = blockIdx.x, cy = blockIdx.y, bz = blockIdx.z;
    const unsigned ONE = 0x3F80u;

    // ---- pack B-chunk into LDS: thread packs targets 4*tid..4*tid+3 ----
    {
        const float4* tv = reinterpret_cast<const float4*>(
            tgt + ((size_t)bz * MTGT + (size_t)cy * 1024 + tid * 4) * 3);
        float4 r0 = tv[0], r1 = tv[1], r2 = tv[2];
        float px[4] = {r0.x, r0.w, r1.z, r2.y};
        float py[4] = {r0.y, r1.x, r1.w, r2.z};
        float pz[4] = {r0.z, r1.y, r2.x, r2.w};
#pragma unroll
        for (int j = 0; j < 4; ++j) {
            uint4 b0, b1;
            packB(px[j], py[j], pz[j], b0, b1);
            const int q = tid * 4 + j, m = q >> 5, l = q & 31;
            ldsB[m * 64 + l]      = b0;
            ldsB[m * 64 + 32 + l] = b1;
        }
    }

    // ---- A-fragments in-register: 2 strips, lane-half selects a0/a1 part ----
    const int Ts0 = bz * 256 + sg * 8 + wid * 2;      // global strip indices
    bf16x8 s0, s1;
    {
        const int half = lane >> 5;                   // 0: a0-part, 1: a1-part
#pragma unroll
        for (int t = 0; t < 2; ++t) {
            const size_t i = (size_t)(Ts0 + t) * 32 + (lane & 31);
            float sx = src[3*i], sy = src[3*i+1], sz = src[3*i+2];
            float axf = -2.f*sx, ayf = -2.f*sy, azf = -2.f*sz;
            unsigned axh = f2bf(axf), ayh = f2bf(ayf), azh = f2bf(azf);
            unsigned axl = f2bf(axf - bf2f(axh));
            unsigned ayl = f2bf(ayf - bf2f(ayh));
            unsigned azl = f2bf(azf - bf2f(azh));
            uint4 a0 = make_uint4(axh | (ayh<<16), azh | (axl<<16),
                                  ayl | (azl<<16), axh | (ayh<<16));
            uint4 a1 = make_uint4(azh | (ONE<<16), ONE | (ONE<<16), 0u, 0u);
            uint4 frag = half ? a1 : a0;
            if (t == 0) s0 = *(bf16x8*)&frag; else s1 = *(bf16x8*)&frag;
        }
    }

    f32x16 z;
#pragma unroll
    for (int e = 0; e < 16; ++e) z[e] = 0.f;
    float acc0 = 3e38f, acc1 = 3e38f;

    __syncthreads();
    const bf16x8* bp = (const bf16x8*)ldsB;           // [tile*64 + lane]

#pragma unroll 2
    for (int m = 0; m < 32; m += 2) {
        bf16x8 tfA = bp[m * 64 + lane];               // ds_read_b128, conflict-free
        bf16x8 tfB = bp[(m + 1) * 64 + lane];
        f32x16 d0 = __builtin_amdgcn_mfma_f32_32x32x16_bf16(tfA, s0, z, 0, 0, 0);
        f32x16 d1 = __builtin_amdgcn_mfma_f32_32x32x16_bf16(tfA, s1, z, 0, 0, 0);
        f32x16 d2 = __builtin_amdgcn_mfma_f32_32x32x16_bf16(tfB, s0, z, 0, 0, 0);
        f32x16 d3 = __builtin_amdgcn_mfma_f32_32x32x16_bf16(tfB, s1, z, 0, 0, 0);
        acc0 = min16(d0, acc0);
        acc1 = min16(d1, acc1);
        acc0 = min16(d2, acc0);
        acc1 = min16(d3, acc1);
    }

    // combine lane-halves (complementary target rows) -- one swap per strip
    float f0 = fminf(acc0, __shfl_xor(acc0, 32));
    float f1 = fminf(acc1, __shfl_xor(acc1, 32));

    // lane = source col -> coalesced 128B stores from lanes 0..31
    if (lane < 32) {
        float* wb = wspart + (size_t)cy * BN + (size_t)bz * NPTS + sg * 256 + wid * 64;
        wb[lane]      = f0;
        wb[32 + lane] = f1;
    }
}

// 128 blocks x 256: min over 8 chunk-partials (coalesced), + ||s||^2, validity,
// fixed-order double partials -> bit-deterministic. (R18's exact tail.)
__global__ __launch_bounds__(256) void reduce_kernel(const float* __restrict__ src,
                                                     const float* __restrict__ wspart,
                                                     double* __restrict__ partials) {
    const int blk = blockIdx.x, tid = threadIdx.x;
    const int gid = blk * 256 + tid;

    float m = 3e38f;
#pragma unroll
    for (int c = 0; c < NCHUNK; ++c) m = fminf(m, wspart[(size_t)c * BN + gid]);

    float sx = src[3*(size_t)gid], sy = src[3*(size_t)gid+1], sz = src[3*(size_t)gid+2];
    bool valid = (sx != 0.f) || (sy != 0.f) || (sz != 0.f);
    float ssq = fmaf(sx, sx, fmaf(sy, sy, sz * sz));
    float sq = fmaxf(0.f, ssq + m);

    __shared__ double sh[512];
    sh[tid] = valid ? (double)sq : 0.0;
    sh[256 + tid] = valid ? 1.0 : 0.0;
    __syncthreads();
    for (int s = 128; s > 0; s >>= 1) {
        if (tid < s) { sh[tid] += sh[tid + s]; sh[256 + tid] += sh[256 + tid + s]; }
        __syncthreads();
    }
    if (tid == 0) { partials[2 * blk] = sh[0]; partials[2 * blk + 1] = sh[256]; }
}

// Fixed-order final combine (batch t owns partial blocks 32t..32t+31).
__global__ void final_kernel(const double* __restrict__ partials, float* __restrict__ out) {
    __shared__ double bmv[4];
    int t = threadIdx.x;
    if (t < 4) {
        double s = 0.0, c = 0.0;
        for (int i = 0; i < 32; ++i) {
            s += partials[2 * (t * 32 + i)];
            c += partials[2 * (t * 32 + i) + 1];
        }
        if (c < 1.0) c = 1.0;
        bmv[t] = s / (3.0 * c);
    }
    __syncthreads();
    if (t == 0) out[0] = (float)((bmv[0] + bmv[1] + bmv[2] + bmv[3]) * 0.25);
}

extern "C" void kernel_launch(void* const* d_in, const int* in_sizes, int n_in,
                              void* d_out, int out_size, void* d_ws, size_t ws_size,
                              hipStream_t stream) {
    const float* src = (const float*)d_in[0];
    const float* tgt = (const float*)d_in[1];
    float* out = (float*)d_out;

    // ws: wspart 1MB | partials 2KB
    float* wspart    = (float*)d_ws;
    double* partials = (double*)((char*)d_ws + (1u << 20));

    nn_mfma_kernel<<<dim3(SGRP, NCHUNK, NBATCH), dim3(256), 0, stream>>>(src, tgt, wspart);
    reduce_kernel<<<dim3(BN / 256), dim3(256), 0, stream>>>(src, wspart, partials);
    final_kernel<<<dim3(1), dim3(64), 0, stream>>>(partials, out);
}

// Round 24
// 17.947 us; speedup vs baseline: 2.6658x; 1.0016x over previous
//
#include <hip/hip_runtime.h>

// Fixed-shape problem
#define NBATCH 4
#define NPTS   8192
#define MTGT   8192
#define BN     (NBATCH*NPTS)      // 32768 sources (== total targets)
#define NCHUNK 8                  // target chunks per batch (1024 targets each)
#define SGRP   32                 // source groups per batch (256 sources each)
// nn grid: (32, 8, 4) = 1024 blocks of 256 threads (4 waves)

typedef __attribute__((ext_vector_type(8)))  short bf16x8;   // guide-verified frag type
typedef __attribute__((ext_vector_type(16))) float f32x16;

__device__ __forceinline__ unsigned short f2bf(float x) {   // RNE fp32->bf16
    unsigned u = __float_as_uint(x);
    return (unsigned short)((u + 0x7fffu + ((u >> 16) & 1u)) >> 16);
}
__device__ __forceinline__ float bf2f(unsigned short h) {
    return __uint_as_float(((unsigned)h) << 16);
}

// min over the 16 C-regs + accumulator: 8 v_min3-fusable ops, exact/associative.
__device__ __forceinline__ float min16(const f32x16& d, float acc) {
    float r0 = fminf(fminf(d[0],  d[1]),  d[2]);
    float r1 = fminf(fminf(d[3],  d[4]),  d[5]);
    float r2 = fminf(fminf(d[6],  d[7]),  d[8]);
    float r3 = fminf(fminf(d[9],  d[10]), d[11]);
    float r4 = fminf(fminf(d[12], d[13]), d[14]);
    float s0 = fminf(fminf(r0, r1), r2);
    float s1 = fminf(fminf(r3, r4), d[15]);
    return fminf(fminf(s0, s1), acc);
}

// Pack one target (x,y,z) into its b0/b1 fragment words (byte-identical math;
// slot pairing validated R13-R23, absmax 0.0).
__device__ __forceinline__ void packB(float tx, float ty, float tz,
                                      uint4& b0, uint4& b1) {
    unsigned txh = f2bf(tx), tyh = f2bf(ty), tzh = f2bf(tz);
    unsigned txl = f2bf(tx - bf2f(txh));
    unsigned tyl = f2bf(ty - bf2f(tyh));
    unsigned tzl = f2bf(tz - bf2f(tzh));
    float tsq = fmaf(tx, tx, fmaf(ty, ty, tz * tz));
    bool valid = (tx != 0.f) || (ty != 0.f) || (tz != 0.f);
    unsigned qh, qm, ql;
    if (valid) {
        qh = f2bf(tsq);
        float r1 = tsq - bf2f(qh); qm = f2bf(r1);
        float r2 = r1 - bf2f(qm);  ql = f2bf(r2);
    } else { qh = f2bf(1e30f); qm = 0u; ql = 0u; }
    b0 = make_uint4(txh | (tyh<<16), tzh | (txh<<16), tyh | (tzh<<16), txl | (tyl<<16));
    b1 = make_uint4(tzl | (qh<<16), qm | (ql<<16), 0u, 0u);
}

// FUSED prep+nn (R23, 18.0us) + even/odd-tile accumulator split: the four
// min16 trees per body are now fully INDEPENDENT (was 2 serial chains) --
// min is exactly associative so the result is bit-identical; +2 VGPRs.
__global__ __launch_bounds__(256, 4) void nn_mfma_kernel(const float* __restrict__ src,
                                                         const float* __restrict__ tgt,
                                                         float* __restrict__ wspart) {
    __shared__ uint4 ldsB[2048];                      // 32KB: 32 tiles x 64 entries

    const int tid  = threadIdx.x;
    const int lane = tid & 63, wid = tid >> 6;
    const int sg = blockIdx.x, cy = blockIdx.y, bz = blockIdx.z;
    const unsigned ONE = 0x3F80u;

    // ---- pack B-chunk into LDS: thread packs targets 4*tid..4*tid+3 ----
    {
        const float4* tv = reinterpret_cast<const float4*>(
            tgt + ((size_t)bz * MTGT + (size_t)cy * 1024 + tid * 4) * 3);
        float4 r0 = tv[0], r1 = tv[1], r2 = tv[2];
        float px[4] = {r0.x, r0.w, r1.z, r2.y};
        float py[4] = {r0.y, r1.x, r1.w, r2.z};
        float pz[4] = {r0.z, r1.y, r2.x, r2.w};
#pragma unroll
        for (int j = 0; j < 4; ++j) {
            uint4 b0, b1;
            packB(px[j], py[j], pz[j], b0, b1);
            const int q = tid * 4 + j, m = q >> 5, l = q & 31;
            ldsB[m * 64 + l]      = b0;
            ldsB[m * 64 + 32 + l] = b1;
        }
    }

    // ---- A-fragments in-register: 2 strips, lane-half selects a0/a1 part ----
    const int Ts0 = bz * 256 + sg * 8 + wid * 2;      // global strip indices
    bf16x8 s0, s1;
    {
        const int half = lane >> 5;                   // 0: a0-part, 1: a1-part
#pragma unroll
        for (int t = 0; t < 2; ++t) {
            const size_t i = (size_t)(Ts0 + t) * 32 + (lane & 31);
            float sx = src[3*i], sy = src[3*i+1], sz = src[3*i+2];
            float axf = -2.f*sx, ayf = -2.f*sy, azf = -2.f*sz;
            unsigned axh = f2bf(axf), ayh = f2bf(ayf), azh = f2bf(azf);
            unsigned axl = f2bf(axf - bf2f(axh));
            unsigned ayl = f2bf(ayf - bf2f(ayh));
            unsigned azl = f2bf(azf - bf2f(azh));
            uint4 a0 = make_uint4(axh | (ayh<<16), azh | (axl<<16),
                                  ayl | (azl<<16), axh | (ayh<<16));
            uint4 a1 = make_uint4(azh | (ONE<<16), ONE | (ONE<<16), 0u, 0u);
            uint4 frag = half ? a1 : a0;
            if (t == 0) s0 = *(bf16x8*)&frag; else s1 = *(bf16x8*)&frag;
        }
    }

    f32x16 z;
#pragma unroll
    for (int e = 0; e < 16; ++e) z[e] = 0.f;
    float acc0A = 3e38f, acc0B = 3e38f, acc1A = 3e38f, acc1B = 3e38f;

    __syncthreads();
    const bf16x8* bp = (const bf16x8*)ldsB;           // [tile*64 + lane]

#pragma unroll 2
    for (int m = 0; m < 32; m += 2) {
        bf16x8 tfA = bp[m * 64 + lane];               // ds_read_b128, conflict-free
        bf16x8 tfB = bp[(m + 1) * 64 + lane];
        f32x16 d0 = __builtin_amdgcn_mfma_f32_32x32x16_bf16(tfA, s0, z, 0, 0, 0);
        f32x16 d1 = __builtin_amdgcn_mfma_f32_32x32x16_bf16(tfA, s1, z, 0, 0, 0);
        f32x16 d2 = __builtin_amdgcn_mfma_f32_32x32x16_bf16(tfB, s0, z, 0, 0, 0);
        f32x16 d3 = __builtin_amdgcn_mfma_f32_32x32x16_bf16(tfB, s1, z, 0, 0, 0);
        acc0A = min16(d0, acc0A);                     // 4 independent trees
        acc1A = min16(d1, acc1A);
        acc0B = min16(d2, acc0B);
        acc1B = min16(d3, acc1B);
    }

    float acc0 = fminf(acc0A, acc0B);
    float acc1 = fminf(acc1A, acc1B);

    // combine lane-halves (complementary target rows) -- one swap per strip
    float f0 = fminf(acc0, __shfl_xor(acc0, 32));
    float f1 = fminf(acc1, __shfl_xor(acc1, 32));

    // lane = source col -> coalesced 128B stores from lanes 0..31
    if (lane < 32) {
        float* wb = wspart + (size_t)cy * BN + (size_t)bz * NPTS + sg * 256 + wid * 64;
        wb[lane]      = f0;
        wb[32 + lane] = f1;
    }
}

// 128 blocks x 256: min over 8 chunk-partials (coalesced), + ||s||^2, validity,
// fixed-order double partials -> bit-deterministic. (R18's exact tail.)
__global__ __launch_bounds__(256) void reduce_kernel(const float* __restrict__ src,
                                                     const float* __restrict__ wspart,
                                                     double* __restrict__ partials) {
    const int blk = blockIdx.x, tid = threadIdx.x;
    const int gid = blk * 256 + tid;

    float m = 3e38f;
#pragma unroll
    for (int c = 0; c < NCHUNK; ++c) m = fminf(m, wspart[(size_t)c * BN + gid]);

    float sx = src[3*(size_t)gid], sy = src[3*(size_t)gid+1], sz = src[3*(size_t)gid+2];
    bool valid = (sx != 0.f) || (sy != 0.f) || (sz != 0.f);
    float ssq = fmaf(sx, sx, fmaf(sy, sy, sz * sz));
    float sq = fmaxf(0.f, ssq + m);

    __shared__ double sh[512];
    sh[tid] = valid ? (double)sq : 0.0;
    sh[256 + tid] = valid ? 1.0 : 0.0;
    __syncthreads();
    for (int s = 128; s > 0; s >>= 1) {
        if (tid < s) { sh[tid] += sh[tid + s]; sh[256 + tid] += sh[256 + tid + s]; }
        __syncthreads();
    }
    if (tid == 0) { partials[2 * blk] = sh[0]; partials[2 * blk + 1] = sh[256]; }
}

// Fixed-order final combine (batch t owns partial blocks 32t..32t+31).
__global__ void final_kernel(const double* __restrict__ partials, float* __restrict__ out) {
    __shared__ double bmv[4];
    int t = threadIdx.x;
    if (t < 4) {
        double s = 0.0, c = 0.0;
        for (int i = 0; i < 32; ++i) {
            s += partials[2 * (t * 32 + i)];
            c += partials[2 * (t * 32 + i) + 1];
        }
        if (c < 1.0) c = 1.0;
        bmv[t] = s / (3.0 * c);
    }
    __syncthreads();
    if (t == 0) out[0] = (float)((bmv[0] + bmv[1] + bmv[2] + bmv[3]) * 0.25);
}

extern "C" void kernel_launch(void* const* d_in, const int* in_sizes, int n_in,
                              void* d_out, int out_size, void* d_ws, size_t ws_size,
                              hipStream_t stream) {
    const float* src = (const float*)d_in[0];
    const float* tgt = (const float*)d_in[1];
    float* out = (float*)d_out;

    // ws: wspart 1MB | partials 2KB
    float* wspart    = (float*)d_ws;
    double* partials = (double*)((char*)d_ws + (1u << 20));

    nn_mfma_kernel<<<dim3(SGRP, NCHUNK, NBATCH), dim3(256), 0, stream>>>(src, tgt, wspart);
    reduce_kernel<<<dim3(BN / 256), dim3(256), 0, stream>>>(src, wspart, partials);
    final_kernel<<<dim3(1), dim3(64), 0, stream>>>(partials, out);
}